// Round 1
// baseline (502.622 us; speedup 1.0000x reference)
//
#include <hip/hip_runtime.h>
#include <hip/hip_bf16.h>
#include <math.h>

// Shapes (fixed by the problem)
#define BB   512
#define NN   64
#define NFG  1024
#define NFR  256
#define MM   (BB * NN)          // 32768
#define RG_OFF 33554432L        // out elements before relation_graph

typedef __attribute__((ext_vector_type(8))) short bf16x8;   // 8 bf16 = 4 VGPRs (guide §3)
typedef __attribute__((ext_vector_type(4))) float f32x4;
typedef __attribute__((ext_vector_type(8))) unsigned short u16x8;

__device__ inline unsigned short f2bf(float f) {
    union { float f; unsigned u; } v; v.f = f;
    unsigned u = v.u;
    return (unsigned short)((u + 0x7FFFu + ((u >> 16) & 1u)) >> 16);  // RNE
}
__device__ inline float bf2f(unsigned short h) {
    union { unsigned u; float f; } v; v.u = ((unsigned)h) << 16;
    return v.f;
}

__device__ inline void gld_lds16(const unsigned short* g, unsigned short* l) {
    // async global->LDS, 16B per lane; LDS dst is wave-uniform base + lane*16
    __builtin_amdgcn_global_load_lds((const __attribute__((address_space(1))) void*)g,
                                     (__attribute__((address_space(3))) void*)l, 16, 0, 0);
}

// ---------------- converts ----------------

__global__ __launch_bounds__(256) void cast_f32_bf16(const float* __restrict__ in,
                                                     unsigned short* __restrict__ out, long n) {
    long i = ((long)blockIdx.x * 256 + threadIdx.x) * 8;
    if (i + 8 <= n) {
        f32x4 a = *(const f32x4*)(in + i);
        f32x4 b = *(const f32x4*)(in + i + 4);
        u16x8 o;
#pragma unroll
        for (int c = 0; c < 4; ++c) { o[c] = f2bf(a[c]); o[4 + c] = f2bf(b[c]); }
        *(u16x8*)(out + i) = o;
    }
}

// in: [K][N] f32 row-major  ->  out: [N][K] bf16 row-major
__global__ void transpose_cast(const float* __restrict__ in, unsigned short* __restrict__ out,
                               int K, int N) {
    __shared__ float tile[32][33];
    int tx = threadIdx.x, ty = threadIdx.y;
    int k0 = blockIdx.y * 32, n0 = blockIdx.x * 32;
#pragma unroll
    for (int r = 0; r < 4; ++r)
        tile[ty + r * 8][tx] = in[(long)(k0 + ty + r * 8) * N + n0 + tx];
    __syncthreads();
#pragma unroll
    for (int r = 0; r < 4; ++r)
        out[(long)(n0 + ty + r * 8) * K + k0 + tx] = f2bf(tile[tx][ty + r * 8]);
}

__global__ void concat_bias(const float* __restrict__ bt, const float* __restrict__ bp,
                            float* __restrict__ out) {
    int i = threadIdx.x;
    out[i] = (i < 256) ? bt[i] : bp[i - 256];
}

// ---------------- gemm_bt: C[M][N] = act(A[M][K] @ Bt[N][K]^T + bias) ----------------
// 128x128 tile, 4 waves 2x2, each wave 64x64 (4x4 mfma 16x16x32 acc), BK=32.

template<int RELU, int STORE_BF16>
__global__ __launch_bounds__(256)
void gemm_bt(const unsigned short* __restrict__ A, const unsigned short* __restrict__ Bt,
             const float* __restrict__ bias, void* __restrict__ Cout,
             int M, int N, int K) {
    __shared__ __align__(16) unsigned short As[128 * 32];
    __shared__ __align__(16) unsigned short Bs[128 * 32];
    const int t    = threadIdx.x;
    const int lane = t & 63;
    const int w    = t >> 6;
    const int l15  = lane & 15;
    const int q    = lane >> 4;
    const long tileM = (long)blockIdx.x * 128;
    const long tileN = (long)blockIdx.y * 128;
    const int wm = (w & 1) * 64;
    const int wn = (w >> 1) * 64;

    f32x4 acc[4][4] = {};

    // staging map: chunkid = issue*256 + t ; row = chunkid>>2 (0..127), chunk = t&3
    const int rS = t >> 2;
    const int cS = t & 3;
    const unsigned short* gA0 = A  + (tileM + rS) * (long)K + cS * 8;
    const unsigned short* gA1 = gA0 + 64L * K;
    const unsigned short* gB0 = Bt + (tileN + rS) * (long)K + cS * 8;
    const unsigned short* gB1 = gB0 + 64L * K;
    unsigned short* lA0 = As + (0 * 256 + w * 64) * 8;   // wave-uniform
    unsigned short* lA1 = As + (1 * 256 + w * 64) * 8;
    unsigned short* lB0 = Bs + (0 * 256 + w * 64) * 8;
    unsigned short* lB1 = Bs + (1 * 256 + w * 64) * 8;

    for (int kt = 0; kt < K; kt += 32) {
        __syncthreads();                 // protect LDS reuse
        gld_lds16(gA0 + kt, lA0);
        gld_lds16(gA1 + kt, lA1);
        gld_lds16(gB0 + kt, lB0);
        gld_lds16(gB1 + kt, lB1);
        __syncthreads();                 // drain staging (compiler emits vmcnt(0))
        bf16x8 af[4], bf[4];
#pragma unroll
        for (int mi = 0; mi < 4; ++mi)
            af[mi] = *(const bf16x8*)(As + (wm + mi * 16 + l15) * 32 + q * 8);
#pragma unroll
        for (int ni = 0; ni < 4; ++ni)
            bf[ni] = *(const bf16x8*)(Bs + (wn + ni * 16 + l15) * 32 + q * 8);
#pragma unroll
        for (int mi = 0; mi < 4; ++mi)
#pragma unroll
            for (int ni = 0; ni < 4; ++ni)
                acc[mi][ni] = __builtin_amdgcn_mfma_f32_16x16x32_bf16(af[mi], bf[ni],
                                                                      acc[mi][ni], 0, 0, 0);
    }

    // epilogue: C/D layout col=lane&15, row=(lane>>4)*4+reg (verified m89/m91)
#pragma unroll
    for (int mi = 0; mi < 4; ++mi) {
#pragma unroll
        for (int ni = 0; ni < 4; ++ni) {
            long row0 = tileM + wm + mi * 16 + q * 4;
            long col  = tileN + wn + ni * 16 + l15;
            float bv = bias ? bias[col] : 0.f;
#pragma unroll
            for (int r = 0; r < 4; ++r) {
                float v = acc[mi][ni][r] + bv;
                if (RELU) v = fmaxf(v, 0.f);
                long idx = (row0 + r) * N + col;
                if (STORE_BF16) ((unsigned short*)Cout)[idx] = f2bf(v);
                else            ((float*)Cout)[idx] = v;
            }
        }
    }
}

// ---------------- fused: sim -> mask -> softmax -> relation_graph + agg ----------------
// one block (256 thr, 4 waves) per batch element

__global__ __launch_bounds__(256)
void fused_softmax_agg(const unsigned short* __restrict__ thetaphi,  // [32768][512] bf16
                       const float* __restrict__ boxes,              // [512][64][4]
                       const unsigned short* __restrict__ featsb,    // [32768][1024] bf16
                       float* __restrict__ rg_out,                   // relation_graph f32
                       unsigned short* __restrict__ aggb) {          // [32768][1024] bf16
    __shared__ __align__(16) float sim_s[64][68];
    __shared__ __align__(16) float Pt[64][68];    // transposed P, row stride 272B (16B mult)
    __shared__ float cxs[64], cys[64];
    const int t    = threadIdx.x;
    const int b    = blockIdx.x;
    const int lane = t & 63;
    const int w    = t >> 6;
    const int l15  = lane & 15;
    const int q    = lane >> 4;

    if (t < 64) {
        float4 bx = *(const float4*)(boxes + ((long)b * 64 + t) * 4);
        cxs[t] = (bx.x + bx.z) * 0.5f;
        cys[t] = (bx.y + bx.w) * 0.5f;
    }

    // sim[i][j] = theta_i . phi_j / 16 ; wave w does rows w*16..w*16+15
    {
        f32x4 acc[4] = {};
        const unsigned short* thA = thetaphi + ((long)b * 64 + w * 16 + l15) * 512 + q * 8;
        const unsigned short* thB = thetaphi + ((long)b * 64 + l15) * 512 + 256 + q * 8;
#pragma unroll
        for (int kt = 0; kt < 256; kt += 32) {
            bf16x8 a = *(const bf16x8*)(thA + kt);
#pragma unroll
            for (int ni = 0; ni < 4; ++ni) {
                bf16x8 bb = *(const bf16x8*)(thB + (long)ni * 16 * 512 + kt);
                acc[ni] = __builtin_amdgcn_mfma_f32_16x16x32_bf16(a, bb, acc[ni], 0, 0, 0);
            }
        }
#pragma unroll
        for (int ni = 0; ni < 4; ++ni)
#pragma unroll
            for (int r = 0; r < 4; ++r)
                sim_s[w * 16 + q * 4 + r][ni * 16 + l15] = acc[ni][r] * 0.0625f;
    }
    __syncthreads();

    // softmax row i, 4 lanes per row each owning 16 cols
    {
        const int i  = t >> 2;
        const int j0 = (t & 3) * 16;
        const float cxi = cxs[i], cyi = cys[i];
        const float thr = (float)(0.2 * 157.0);   // matches jax fp32 compare
        float vals[16];
        float mx = -__builtin_inff();
#pragma unroll
        for (int jj = 0; jj < 16; ++jj) {
            int j = j0 + jj;
            float dx = cxi - cxs[j];
            float dy = cyi - cys[j];
            bool msk = sqrtf(dx * dx + dy * dy) > thr;
            float s = msk ? -__builtin_inff() : sim_s[i][j];
            vals[jj] = s;
            mx = fmaxf(mx, s);
        }
        mx = fmaxf(mx, __shfl_xor(mx, 1, 64));
        mx = fmaxf(mx, __shfl_xor(mx, 2, 64));
        float sum = 0.f;
#pragma unroll
        for (int jj = 0; jj < 16; ++jj) {
            float e = (vals[jj] == -__builtin_inff()) ? 0.f : __expf(vals[jj] - mx);
            vals[jj] = e;
            sum += e;
        }
        sum += __shfl_xor(sum, 1, 64);
        sum += __shfl_xor(sum, 2, 64);
        float inv = 1.f / sum;   // self always unmasked -> sum > 0
#pragma unroll
        for (int jj = 0; jj < 16; ++jj) {
            int j = j0 + jj;
            float p = vals[jj] * inv;
            rg_out[((long)b * 64 + i) * 64 + j] = p;
            Pt[j][i] = p;
        }
    }
    __syncthreads();

    // agg[i][g] = sum_j P[i][j] * feats[j][g] ; 4x8 register micro-tile per thread
    {
        const int i0 = (t >> 4) * 4;
        const int gb = t & 15;
        const unsigned short* fB = featsb + (long)b * 64 * 1024;
        unsigned short* aB = aggb + (long)b * 64 * 1024;
#pragma unroll 1
        for (int gc = 0; gc < 8; ++gc) {
            int g = gc * 128 + gb * 8;
            float acc[4][8];
#pragma unroll
            for (int r = 0; r < 4; ++r)
#pragma unroll
                for (int c = 0; c < 8; ++c) acc[r][c] = 0.f;
#pragma unroll 4
            for (int j = 0; j < 64; ++j) {
                f32x4 p = *(const f32x4*)(&Pt[j][i0]);          // 16B aligned
                u16x8 fv = *(const u16x8*)(fB + j * 1024 + g);  // 16B aligned
                float f[8];
#pragma unroll
                for (int c = 0; c < 8; ++c) f[c] = bf2f(fv[c]);
#pragma unroll
                for (int r = 0; r < 4; ++r)
#pragma unroll
                    for (int c = 0; c < 8; ++c) acc[r][c] += p[r] * f[c];
            }
#pragma unroll
            for (int r = 0; r < 4; ++r) {
                u16x8 o;
#pragma unroll
                for (int c = 0; c < 8; ++c) o[c] = f2bf(acc[r][c]);
                *(u16x8*)(aB + (i0 + r) * 1024 + g) = o;
            }
        }
    }
}

// ---------------- launch ----------------

extern "C" void kernel_launch(void* const* d_in, const int* in_sizes, int n_in,
                              void* d_out, int out_size, void* d_ws, size_t ws_size,
                              hipStream_t stream) {
    const float* feats   = (const float*)d_in[0];
    const float* boxes   = (const float*)d_in[1];
    const float* W_theta = (const float*)d_in[2];
    const float* b_theta = (const float*)d_in[3];
    const float* W_phi   = (const float*)d_in[4];
    const float* b_phi   = (const float*)d_in[5];
    const float* W_gcn   = (const float*)d_in[6];
    float* out = (float*)d_out;

    // workspace layout (~163 MB)
    char* ws = (char*)d_ws;
    unsigned short* featsb   = (unsigned short*)(ws);                // 67108864 B
    unsigned short* thetaphi = (unsigned short*)(ws + 67108864);     // 33554432 B
    unsigned short* aggb     = (unsigned short*)(ws + 100663296);    // 67108864 B
    unsigned short* Wtp      = (unsigned short*)(ws + 167772160);    //  1048576 B
    unsigned short* Wgt      = (unsigned short*)(ws + 168820736);    //  2097152 B
    float*          bias512  = (float*)(ws + 170917888);             //     2048 B

    cast_f32_bf16<<<16384, 256, 0, stream>>>(feats, featsb, 33554432L);
    transpose_cast<<<dim3(8, 32),  dim3(32, 8), 0, stream>>>(W_theta, Wtp,              1024, 256);
    transpose_cast<<<dim3(8, 32),  dim3(32, 8), 0, stream>>>(W_phi,   Wtp + 256 * 1024, 1024, 256);
    transpose_cast<<<dim3(32, 32), dim3(32, 8), 0, stream>>>(W_gcn,   Wgt,              1024, 1024);
    concat_bias<<<1, 512, 0, stream>>>(b_theta, b_phi, bias512);

    // theta|phi: [32768][512] bf16
    gemm_bt<0, 1><<<dim3(256, 4), 256, 0, stream>>>(featsb, Wtp, bias512, thetaphi,
                                                    MM, 512, 1024);
    // relation graph + agg
    fused_softmax_agg<<<BB, 256, 0, stream>>>(thetaphi, boxes, featsb, out + RG_OFF, aggb);
    // out = relu(agg @ W_gcn): [32768][1024] f32
    gemm_bt<1, 0><<<dim3(256, 8), 256, 0, stream>>>(aggb, Wgt, nullptr, out,
                                                    MM, 1024, 1024);
}

// Round 2
// 497.986 us; speedup vs baseline: 1.0093x; 1.0093x over previous
//
#include <hip/hip_runtime.h>
#include <hip/hip_bf16.h>
#include <math.h>

// Shapes (fixed by the problem)
#define BB   512
#define NN   64
#define NFG  1024
#define NFR  256
#define MM   (BB * NN)          // 32768
#define RG_OFF 33554432L        // out elements before relation_graph

typedef __attribute__((ext_vector_type(8))) short bf16x8;   // 8 bf16 = 4 VGPRs (guide §3)
typedef __attribute__((ext_vector_type(4))) float f32x4;
typedef __attribute__((ext_vector_type(8))) unsigned short u16x8;
typedef __attribute__((ext_vector_type(4))) unsigned short u16x4;

__device__ inline unsigned short f2bf(float f) {
    union { float f; unsigned u; } v; v.f = f;
    unsigned u = v.u;
    return (unsigned short)((u + 0x7FFFu + ((u >> 16) & 1u)) >> 16);  // RNE
}

__device__ inline void gld_lds16(const unsigned short* g, unsigned short* l) {
    // async global->LDS, 16B per lane; LDS dst is wave-uniform base + lane*16
    __builtin_amdgcn_global_load_lds((const __attribute__((address_space(1))) void*)g,
                                     (__attribute__((address_space(3))) void*)l, 16, 0, 0);
}

// ---------------- converts ----------------

__global__ __launch_bounds__(256) void cast_f32_bf16(const float* __restrict__ in,
                                                     unsigned short* __restrict__ out, long n) {
    long i = ((long)blockIdx.x * 256 + threadIdx.x) * 8;
    if (i + 8 <= n) {
        f32x4 a = *(const f32x4*)(in + i);
        f32x4 b = *(const f32x4*)(in + i + 4);
        u16x8 o;
#pragma unroll
        for (int c = 0; c < 4; ++c) { o[c] = f2bf(a[c]); o[4 + c] = f2bf(b[c]); }
        *(u16x8*)(out + i) = o;
    }
}

// in: [K][N] f32 row-major  ->  out: [N][K] bf16 row-major
__global__ void transpose_cast(const float* __restrict__ in, unsigned short* __restrict__ out,
                               int K, int N) {
    __shared__ float tile[32][33];
    int tx = threadIdx.x, ty = threadIdx.y;
    int k0 = blockIdx.y * 32, n0 = blockIdx.x * 32;
#pragma unroll
    for (int r = 0; r < 4; ++r)
        tile[ty + r * 8][tx] = in[(long)(k0 + ty + r * 8) * N + n0 + tx];
    __syncthreads();
#pragma unroll
    for (int r = 0; r < 4; ++r)
        out[(long)(n0 + ty + r * 8) * K + k0 + tx] = f2bf(tile[tx][ty + r * 8]);
}

__global__ void concat_bias(const float* __restrict__ bt, const float* __restrict__ bp,
                            float* __restrict__ out) {
    int i = threadIdx.x;
    out[i] = (i < 256) ? bt[i] : bp[i - 256];
}

// ---------------- gemm_bt: C[M][N] = act(A[M][K] @ Bt[N][K]^T + bias) ----------------
// 128x128 tile, 4 waves 2x2, each wave 64x64 (4x4 mfma 16x16x32 acc), BK=32.
// OUT_MODE: 0 = f32 row-major, 1 = bf16 row-major,
//           2 = bf16 batch-64-transposed: C[b=row/64][col][row%64] (for per-batch Bt use)

template<int RELU, int OUT_MODE>
__global__ __launch_bounds__(256)
void gemm_bt(const unsigned short* __restrict__ A, const unsigned short* __restrict__ Bt,
             const float* __restrict__ bias, void* __restrict__ Cout,
             int M, int N, int K) {
    __shared__ __align__(16) unsigned short As[128 * 32];
    __shared__ __align__(16) unsigned short Bs[128 * 32];
    const int t    = threadIdx.x;
    const int lane = t & 63;
    const int w    = t >> 6;
    const int l15  = lane & 15;
    const int q    = lane >> 4;
    const long tileM = (long)blockIdx.x * 128;
    const long tileN = (long)blockIdx.y * 128;
    const int wm = (w & 1) * 64;
    const int wn = (w >> 1) * 64;

    f32x4 acc[4][4] = {};

    const int rS = t >> 2;
    const int cS = t & 3;
    const unsigned short* gA0 = A  + (tileM + rS) * (long)K + cS * 8;
    const unsigned short* gA1 = gA0 + 64L * K;
    const unsigned short* gB0 = Bt + (tileN + rS) * (long)K + cS * 8;
    const unsigned short* gB1 = gB0 + 64L * K;
    unsigned short* lA0 = As + (0 * 256 + w * 64) * 8;   // wave-uniform
    unsigned short* lA1 = As + (1 * 256 + w * 64) * 8;
    unsigned short* lB0 = Bs + (0 * 256 + w * 64) * 8;
    unsigned short* lB1 = Bs + (1 * 256 + w * 64) * 8;

    for (int kt = 0; kt < K; kt += 32) {
        __syncthreads();                 // protect LDS reuse
        gld_lds16(gA0 + kt, lA0);
        gld_lds16(gA1 + kt, lA1);
        gld_lds16(gB0 + kt, lB0);
        gld_lds16(gB1 + kt, lB1);
        __syncthreads();                 // drain staging (compiler emits vmcnt(0))
        bf16x8 af[4], bf[4];
#pragma unroll
        for (int mi = 0; mi < 4; ++mi)
            af[mi] = *(const bf16x8*)(As + (wm + mi * 16 + l15) * 32 + q * 8);
#pragma unroll
        for (int ni = 0; ni < 4; ++ni)
            bf[ni] = *(const bf16x8*)(Bs + (wn + ni * 16 + l15) * 32 + q * 8);
#pragma unroll
        for (int mi = 0; mi < 4; ++mi)
#pragma unroll
            for (int ni = 0; ni < 4; ++ni)
                acc[mi][ni] = __builtin_amdgcn_mfma_f32_16x16x32_bf16(af[mi], bf[ni],
                                                                      acc[mi][ni], 0, 0, 0);
    }

    // epilogue: C/D layout col=lane&15, row=(lane>>4)*4+reg (verified m89/m91)
#pragma unroll
    for (int mi = 0; mi < 4; ++mi) {
#pragma unroll
        for (int ni = 0; ni < 4; ++ni) {
            long row0 = tileM + wm + mi * 16 + q * 4;
            long col  = tileN + wn + ni * 16 + l15;
            float bv = bias ? bias[col] : 0.f;
            if (OUT_MODE == 2) {
                // b = row0/64 constant across r (row0%64 <= 60)
                u16x4 o;
#pragma unroll
                for (int r = 0; r < 4; ++r) {
                    float v = acc[mi][ni][r] + bv;
                    if (RELU) v = fmaxf(v, 0.f);
                    o[r] = f2bf(v);
                }
                long base = (row0 >> 6) * ((long)N * 64) + col * 64 + (row0 & 63);
                *(u16x4*)((unsigned short*)Cout + base) = o;
            } else {
#pragma unroll
                for (int r = 0; r < 4; ++r) {
                    float v = acc[mi][ni][r] + bv;
                    if (RELU) v = fmaxf(v, 0.f);
                    long idx = (row0 + r) * N + col;
                    if (OUT_MODE == 1) ((unsigned short*)Cout)[idx] = f2bf(v);
                    else               ((float*)Cout)[idx] = v;
                }
            }
        }
    }
}

// ---------------- fused: sim -> mask -> softmax -> rg + out = relu(P @ H) ----------------
// one block (256 thr, 4 waves) per batch element; H pre-transposed per batch: Ht[b][g][j]

__global__ __launch_bounds__(256)
void fused_softmax_out(const unsigned short* __restrict__ thetaphi,  // [32768][512] bf16
                       const float* __restrict__ boxes,              // [512][64][4]
                       const unsigned short* __restrict__ Ht,        // [512][1024][64] bf16
                       float* __restrict__ rg_out,                   // relation_graph f32
                       float* __restrict__ out) {                    // [512][64][1024] f32
    __shared__ __align__(16) float sim_s[64][68];
    __shared__ __align__(16) unsigned short Pb[64][72];   // 144B row stride: 16B-aligned, 2-way banks
    __shared__ float cxs[64], cys[64];
    const int t    = threadIdx.x;
    const int b    = blockIdx.x;
    const int lane = t & 63;
    const int w    = t >> 6;
    const int l15  = lane & 15;
    const int q    = lane >> 4;

    if (t < 64) {
        float4 bx = *(const float4*)(boxes + ((long)b * 64 + t) * 4);
        cxs[t] = (bx.x + bx.z) * 0.5f;
        cys[t] = (bx.y + bx.w) * 0.5f;
    }

    // sim[i][j] = theta_i . phi_j / 16 ; wave w does rows w*16..w*16+15
    {
        f32x4 acc[4] = {};
        const unsigned short* thA = thetaphi + ((long)b * 64 + w * 16 + l15) * 512 + q * 8;
        const unsigned short* thB = thetaphi + ((long)b * 64 + l15) * 512 + 256 + q * 8;
#pragma unroll
        for (int kt = 0; kt < 256; kt += 32) {
            bf16x8 a = *(const bf16x8*)(thA + kt);
#pragma unroll
            for (int ni = 0; ni < 4; ++ni) {
                bf16x8 bb = *(const bf16x8*)(thB + (long)ni * 16 * 512 + kt);
                acc[ni] = __builtin_amdgcn_mfma_f32_16x16x32_bf16(a, bb, acc[ni], 0, 0, 0);
            }
        }
#pragma unroll
        for (int ni = 0; ni < 4; ++ni)
#pragma unroll
            for (int r = 0; r < 4; ++r)
                sim_s[w * 16 + q * 4 + r][ni * 16 + l15] = acc[ni][r] * 0.0625f;
    }
    __syncthreads();

    // softmax row i, 4 lanes per row each owning 16 cols; emit rg (f32) and P (bf16, A-layout)
    {
        const int i  = t >> 2;
        const int j0 = (t & 3) * 16;
        const float cxi = cxs[i], cyi = cys[i];
        const float thr = (float)(0.2 * 157.0);
        float vals[16];
        float mx = -__builtin_inff();
#pragma unroll
        for (int jj = 0; jj < 16; ++jj) {
            int j = j0 + jj;
            float dx = cxi - cxs[j];
            float dy = cyi - cys[j];
            bool msk = sqrtf(dx * dx + dy * dy) > thr;
            float s = msk ? -__builtin_inff() : sim_s[i][j];
            vals[jj] = s;
            mx = fmaxf(mx, s);
        }
        mx = fmaxf(mx, __shfl_xor(mx, 1, 64));
        mx = fmaxf(mx, __shfl_xor(mx, 2, 64));
        float sum = 0.f;
#pragma unroll
        for (int jj = 0; jj < 16; ++jj) {
            float e = (vals[jj] == -__builtin_inff()) ? 0.f : __expf(vals[jj] - mx);
            vals[jj] = e;
            sum += e;
        }
        sum += __shfl_xor(sum, 1, 64);
        sum += __shfl_xor(sum, 2, 64);
        float inv = 1.f / sum;   // self always unmasked -> sum > 0
#pragma unroll
        for (int jj = 0; jj < 16; ++jj) {
            int j = j0 + jj;
            float p = vals[jj] * inv;
            rg_out[((long)b * 64 + i) * 64 + j] = p;
            Pb[i][j] = f2bf(p);
        }
    }
    __syncthreads();

    // out[i][g] = relu( sum_j P[i][j] * H[j][g] ), K=64; B-frags streamed from Ht
    {
        const unsigned short* HtB = Ht + (long)b * 65536;   // [1024][64]
        float* outB = out + (long)b * 65536;                // [64][1024]
        bf16x8 af[4][2];
#pragma unroll
        for (int mi = 0; mi < 4; ++mi)
#pragma unroll
            for (int kk = 0; kk < 2; ++kk)
                af[mi][kk] = *(const bf16x8*)(&Pb[mi * 16 + l15][kk * 32 + q * 8]);
#pragma unroll 2
        for (int nt = 0; nt < 16; ++nt) {
            const int g0 = w * 256 + nt * 16;
            const unsigned short* hp = HtB + (long)(g0 + l15) * 64 + q * 8;
            bf16x8 b0 = *(const bf16x8*)(hp);
            bf16x8 b1 = *(const bf16x8*)(hp + 32);
#pragma unroll
            for (int mi = 0; mi < 4; ++mi) {
                f32x4 acc = {};
                acc = __builtin_amdgcn_mfma_f32_16x16x32_bf16(af[mi][0], b0, acc, 0, 0, 0);
                acc = __builtin_amdgcn_mfma_f32_16x16x32_bf16(af[mi][1], b1, acc, 0, 0, 0);
#pragma unroll
                for (int r = 0; r < 4; ++r)
                    outB[(long)(mi * 16 + q * 4 + r) * 1024 + g0 + l15] = fmaxf(acc[r], 0.f);
            }
        }
    }
}

// ---------------- launch ----------------

extern "C" void kernel_launch(void* const* d_in, const int* in_sizes, int n_in,
                              void* d_out, int out_size, void* d_ws, size_t ws_size,
                              hipStream_t stream) {
    const float* feats   = (const float*)d_in[0];
    const float* boxes   = (const float*)d_in[1];
    const float* W_theta = (const float*)d_in[2];
    const float* b_theta = (const float*)d_in[3];
    const float* W_phi   = (const float*)d_in[4];
    const float* b_phi   = (const float*)d_in[5];
    const float* W_gcn   = (const float*)d_in[6];
    float* out = (float*)d_out;

    // workspace layout (~171 MB)
    char* ws = (char*)d_ws;
    unsigned short* featsb   = (unsigned short*)(ws);                // 67108864 B
    unsigned short* thetaphi = (unsigned short*)(ws + 67108864);     // 33554432 B
    unsigned short* Ht       = (unsigned short*)(ws + 100663296);    // 67108864 B
    unsigned short* Wtp      = (unsigned short*)(ws + 167772160);    //  1048576 B
    unsigned short* Wgt      = (unsigned short*)(ws + 168820736);    //  2097152 B
    float*          bias512  = (float*)(ws + 170917888);             //     2048 B

    cast_f32_bf16<<<16384, 256, 0, stream>>>(feats, featsb, 33554432L);
    transpose_cast<<<dim3(8, 32),  dim3(32, 8), 0, stream>>>(W_theta, Wtp,              1024, 256);
    transpose_cast<<<dim3(8, 32),  dim3(32, 8), 0, stream>>>(W_phi,   Wtp + 256 * 1024, 1024, 256);
    transpose_cast<<<dim3(32, 32), dim3(32, 8), 0, stream>>>(W_gcn,   Wgt,              1024, 1024);
    concat_bias<<<1, 512, 0, stream>>>(b_theta, b_phi, bias512);

    // theta|phi: [32768][512] bf16 row-major
    gemm_bt<0, 1><<<dim3(256, 4), 256, 0, stream>>>(featsb, Wtp, bias512, thetaphi,
                                                    MM, 512, 1024);
    // H = feats @ W_gcn, stored per-batch transposed: Ht[b][g][i] bf16
    gemm_bt<0, 2><<<dim3(256, 8), 256, 0, stream>>>(featsb, Wgt, nullptr, Ht,
                                                    MM, 1024, 1024);
    // relation graph + out = relu(P @ H)
    fused_softmax_out<<<BB, 256, 0, stream>>>(thetaphi, boxes, Ht, out + RG_OFF, out);
}

// Round 3
// 473.815 us; speedup vs baseline: 1.0608x; 1.0510x over previous
//
#include <hip/hip_runtime.h>
#include <hip/hip_bf16.h>
#include <math.h>

// Shapes (fixed by the problem)
#define BB   512
#define NN   64
#define NFG  1024
#define NFR  256
#define MM   (BB * NN)          // 32768
#define RG_OFF 33554432L        // out elements before relation_graph

typedef __attribute__((ext_vector_type(8))) short bf16x8;   // 8 bf16 = 4 VGPRs (guide §3)
typedef __attribute__((ext_vector_type(4))) float f32x4;
typedef __attribute__((ext_vector_type(8))) unsigned short u16x8;

__device__ inline unsigned short f2bf(float f) {
    union { float f; unsigned u; } v; v.f = f;
    unsigned u = v.u;
    return (unsigned short)((u + 0x7FFFu + ((u >> 16) & 1u)) >> 16);  // RNE
}

__device__ inline void gld_lds16(const unsigned short* g, unsigned short* l) {
    // async global->LDS, 16B per lane; LDS dst is wave-uniform base + lane*16
    __builtin_amdgcn_global_load_lds((const __attribute__((address_space(1))) void*)g,
                                     (__attribute__((address_space(3))) void*)l, 16, 0, 0);
}

// ---------------- converts ----------------

__global__ __launch_bounds__(256) void cast_f32_bf16(const float* __restrict__ in,
                                                     unsigned short* __restrict__ out, long n) {
    long i = ((long)blockIdx.x * 256 + threadIdx.x) * 8;
    if (i + 8 <= n) {
        f32x4 a = *(const f32x4*)(in + i);
        f32x4 b = *(const f32x4*)(in + i + 4);
        u16x8 o;
#pragma unroll
        for (int c = 0; c < 4; ++c) { o[c] = f2bf(a[c]); o[4 + c] = f2bf(b[c]); }
        *(u16x8*)(out + i) = o;
    }
}

// in: [K][N] f32 row-major  ->  out: [N][K] bf16 row-major
__global__ void transpose_cast(const float* __restrict__ in, unsigned short* __restrict__ out,
                               int K, int N) {
    __shared__ float tile[32][33];
    int tx = threadIdx.x, ty = threadIdx.y;
    int k0 = blockIdx.y * 32, n0 = blockIdx.x * 32;
#pragma unroll
    for (int r = 0; r < 4; ++r)
        tile[ty + r * 8][tx] = in[(long)(k0 + ty + r * 8) * N + n0 + tx];
    __syncthreads();
#pragma unroll
    for (int r = 0; r < 4; ++r)
        out[(long)(n0 + ty + r * 8) * K + k0 + tx] = f2bf(tile[tx][ty + r * 8]);
}

__global__ void concat_bias(const float* __restrict__ bt, const float* __restrict__ bp,
                            float* __restrict__ out) {
    int i = threadIdx.x;
    out[i] = (i < 256) ? bt[i] : bp[i - 256];
}

// ---------------- gemm_bt: C[M][N] = act(A[M][K] @ Bt[N][K]^T + bias) ----------------
// 128x128 tile, 4 waves 2x2, each wave 64x64 (4x4 mfma 16x16x32 acc), BK=64.
// LDS rows are 128B (all 32 banks) -> XOR chunk swizzle keeps ds_read_b128 conflict-minimal.

template<int RELU, int STORE_BF16>
__global__ __launch_bounds__(256)
void gemm_bt(const unsigned short* __restrict__ A, const unsigned short* __restrict__ Bt,
             const float* __restrict__ bias, void* __restrict__ Cout,
             int M, int N, int K) {
    __shared__ __align__(16) unsigned short As[128 * 64];   // 16 KB
    __shared__ __align__(16) unsigned short Bs[128 * 64];   // 16 KB
    const int t    = threadIdx.x;
    const int lane = t & 63;
    const int w    = t >> 6;
    const int l15  = lane & 15;
    const int q    = lane >> 4;
    const long tileM = (long)blockIdx.x * 128;
    const long tileN = (long)blockIdx.y * 128;
    const int wm = (w & 1) * 64;
    const int wn = (w >> 1) * 64;

    f32x4 acc[4][4] = {};

    // staging: 4 issues per operand. issue i, thread t -> LDS chunkid = i*256+t
    //   -> LDS row = i*32 + (t>>3), LDS slot = t&7.
    // lane fetches GLOBAL chunk (t&7)^(row&7) so slot s of row r holds chunk s^(r&7).
    const int rS = t >> 3;                 // 0..31
    const int cS = (t & 7) ^ (rS & 7);     // swizzled global chunk
    const unsigned short* gA = A  + (tileM + rS) * (long)K + cS * 8;
    const unsigned short* gB = Bt + (tileN + rS) * (long)K + cS * 8;

    for (int kt = 0; kt < K; kt += 64) {
        __syncthreads();                 // protect LDS reuse
#pragma unroll
        for (int i = 0; i < 4; ++i) {
            gld_lds16(gA + (long)i * 32 * K + kt, As + (i * 256 + w * 64) * 8);
            gld_lds16(gB + (long)i * 32 * K + kt, Bs + (i * 256 + w * 64) * 8);
        }
        __syncthreads();                 // drain staging (compiler emits vmcnt(0))
#pragma unroll
        for (int ks = 0; ks < 2; ++ks) {
            const int slot = (ks * 4 + q) ^ (l15 & 7);   // row&7 == l15&7 (16|wm,mi*16)
            bf16x8 af[4], bf[4];
#pragma unroll
            for (int mi = 0; mi < 4; ++mi)
                af[mi] = *(const bf16x8*)(As + (wm + mi * 16 + l15) * 64 + slot * 8);
#pragma unroll
            for (int ni = 0; ni < 4; ++ni)
                bf[ni] = *(const bf16x8*)(Bs + (wn + ni * 16 + l15) * 64 + slot * 8);
#pragma unroll
            for (int mi = 0; mi < 4; ++mi)
#pragma unroll
                for (int ni = 0; ni < 4; ++ni)
                    acc[mi][ni] = __builtin_amdgcn_mfma_f32_16x16x32_bf16(af[mi], bf[ni],
                                                                          acc[mi][ni], 0, 0, 0);
        }
    }

    // epilogue: C/D layout col=lane&15, row=(lane>>4)*4+reg (verified m89/m91)
#pragma unroll
    for (int mi = 0; mi < 4; ++mi) {
#pragma unroll
        for (int ni = 0; ni < 4; ++ni) {
            long row0 = tileM + wm + mi * 16 + q * 4;
            long col  = tileN + wn + ni * 16 + l15;
            float bv = bias ? bias[col] : 0.f;
#pragma unroll
            for (int r = 0; r < 4; ++r) {
                float v = acc[mi][ni][r] + bv;
                if (RELU) v = fmaxf(v, 0.f);
                long idx = (row0 + r) * N + col;
                if (STORE_BF16) ((unsigned short*)Cout)[idx] = f2bf(v);
                else            ((float*)Cout)[idx] = v;
            }
        }
    }
}

// ---------------- fused: sim -> mask -> softmax -> rg + out = relu(P @ H) ----------------
// one block (256 thr, 4 waves) per batch element; H stored transposed: HtT[g][i], i=b*64+j

__global__ __launch_bounds__(256)
void fused_softmax_out(const unsigned short* __restrict__ thetaphi,  // [32768][512] bf16
                       const float* __restrict__ boxes,              // [512][64][4]
                       const unsigned short* __restrict__ HtT,       // [1024][32768] bf16
                       float* __restrict__ rg_out,                   // relation_graph f32
                       float* __restrict__ out) {                    // [512][64][1024] f32
    __shared__ __align__(16) float sim_s[64][68];
    __shared__ __align__(16) unsigned short Pb[64][72];   // 144B row stride: 16B-aligned
    __shared__ float cxs[64], cys[64];
    const int t    = threadIdx.x;
    const int b    = blockIdx.x;
    const int lane = t & 63;
    const int w    = t >> 6;
    const int l15  = lane & 15;
    const int q    = lane >> 4;

    if (t < 64) {
        float4 bx = *(const float4*)(boxes + ((long)b * 64 + t) * 4);
        cxs[t] = (bx.x + bx.z) * 0.5f;
        cys[t] = (bx.y + bx.w) * 0.5f;
    }

    // sim[i][j] = theta_i . phi_j / 16 ; wave w does rows w*16..w*16+15
    {
        f32x4 acc[4] = {};
        const unsigned short* thA = thetaphi + ((long)b * 64 + w * 16 + l15) * 512 + q * 8;
        const unsigned short* thB = thetaphi + ((long)b * 64 + l15) * 512 + 256 + q * 8;
#pragma unroll
        for (int kt = 0; kt < 256; kt += 32) {
            bf16x8 a = *(const bf16x8*)(thA + kt);
#pragma unroll
            for (int ni = 0; ni < 4; ++ni) {
                bf16x8 bb = *(const bf16x8*)(thB + (long)ni * 16 * 512 + kt);
                acc[ni] = __builtin_amdgcn_mfma_f32_16x16x32_bf16(a, bb, acc[ni], 0, 0, 0);
            }
        }
#pragma unroll
        for (int ni = 0; ni < 4; ++ni)
#pragma unroll
            for (int r = 0; r < 4; ++r)
                sim_s[w * 16 + q * 4 + r][ni * 16 + l15] = acc[ni][r] * 0.0625f;
    }
    __syncthreads();

    // softmax row i, 4 lanes per row each owning 16 cols; emit rg (f32) and P (bf16, A-layout)
    {
        const int i  = t >> 2;
        const int j0 = (t & 3) * 16;
        const float cxi = cxs[i], cyi = cys[i];
        const float thr = (float)(0.2 * 157.0);
        float vals[16];
        float mx = -__builtin_inff();
#pragma unroll
        for (int jj = 0; jj < 16; ++jj) {
            int j = j0 + jj;
            float dx = cxi - cxs[j];
            float dy = cyi - cys[j];
            bool msk = sqrtf(dx * dx + dy * dy) > thr;
            float s = msk ? -__builtin_inff() : sim_s[i][j];
            vals[jj] = s;
            mx = fmaxf(mx, s);
        }
        mx = fmaxf(mx, __shfl_xor(mx, 1, 64));
        mx = fmaxf(mx, __shfl_xor(mx, 2, 64));
        float sum = 0.f;
#pragma unroll
        for (int jj = 0; jj < 16; ++jj) {
            float e = (vals[jj] == -__builtin_inff()) ? 0.f : __expf(vals[jj] - mx);
            vals[jj] = e;
            sum += e;
        }
        sum += __shfl_xor(sum, 1, 64);
        sum += __shfl_xor(sum, 2, 64);
        float inv = 1.f / sum;   // self always unmasked -> sum > 0
#pragma unroll
        for (int jj = 0; jj < 16; ++jj) {
            int j = j0 + jj;
            float p = vals[jj] * inv;
            rg_out[((long)b * 64 + i) * 64 + j] = p;
            Pb[i][j] = f2bf(p);
        }
    }
    __syncthreads();

    // out[i][g] = relu( sum_j P[i][j] * H[j][g] ), K=64; B-frags from HtT[g][b*64+j]
    {
        const unsigned short* HtB = HtT + (long)b * 64;     // column offset
        float* outB = out + (long)b * 65536;                // [64][1024]
        bf16x8 af[4][2];
#pragma unroll
        for (int mi = 0; mi < 4; ++mi)
#pragma unroll
            for (int kk = 0; kk < 2; ++kk)
                af[mi][kk] = *(const bf16x8*)(&Pb[mi * 16 + l15][kk * 32 + q * 8]);
#pragma unroll 2
        for (int nt = 0; nt < 16; ++nt) {
            const int g0 = w * 256 + nt * 16;
            const unsigned short* hp = HtB + (long)(g0 + l15) * 32768 + q * 8;
            bf16x8 b0 = *(const bf16x8*)(hp);        // j = q*8..q*8+7
            bf16x8 b1 = *(const bf16x8*)(hp + 32);   // j = 32+q*8..
#pragma unroll
            for (int mi = 0; mi < 4; ++mi) {
                f32x4 acc = {};
                acc = __builtin_amdgcn_mfma_f32_16x16x32_bf16(af[mi][0], b0, acc, 0, 0, 0);
                acc = __builtin_amdgcn_mfma_f32_16x16x32_bf16(af[mi][1], b1, acc, 0, 0, 0);
#pragma unroll
                for (int r = 0; r < 4; ++r)
                    outB[(long)(mi * 16 + q * 4 + r) * 1024 + g0 + l15] = fmaxf(acc[r], 0.f);
            }
        }
    }
}

// ---------------- launch ----------------

extern "C" void kernel_launch(void* const* d_in, const int* in_sizes, int n_in,
                              void* d_out, int out_size, void* d_ws, size_t ws_size,
                              hipStream_t stream) {
    const float* feats   = (const float*)d_in[0];
    const float* boxes   = (const float*)d_in[1];
    const float* W_theta = (const float*)d_in[2];
    const float* b_theta = (const float*)d_in[3];
    const float* W_phi   = (const float*)d_in[4];
    const float* b_phi   = (const float*)d_in[5];
    const float* W_gcn   = (const float*)d_in[6];
    float* out = (float*)d_out;

    // workspace layout (~171 MB)
    char* ws = (char*)d_ws;
    unsigned short* featsb   = (unsigned short*)(ws);                // 67108864 B
    unsigned short* thetaphi = (unsigned short*)(ws + 67108864);     // 33554432 B
    unsigned short* HtT      = (unsigned short*)(ws + 100663296);    // 67108864 B
    unsigned short* Wtp      = (unsigned short*)(ws + 167772160);    //  1048576 B
    unsigned short* Wgt      = (unsigned short*)(ws + 168820736);    //  2097152 B
    float*          bias512  = (float*)(ws + 170917888);             //     2048 B

    cast_f32_bf16<<<16384, 256, 0, stream>>>(feats, featsb, 33554432L);
    transpose_cast<<<dim3(8, 32),  dim3(32, 8), 0, stream>>>(W_theta, Wtp,              1024, 256);
    transpose_cast<<<dim3(8, 32),  dim3(32, 8), 0, stream>>>(W_phi,   Wtp + 256 * 1024, 1024, 256);
    transpose_cast<<<dim3(32, 32), dim3(32, 8), 0, stream>>>(W_gcn,   Wgt,              1024, 1024);
    concat_bias<<<1, 512, 0, stream>>>(b_theta, b_phi, bias512);

    // theta|phi: [32768][512] bf16 row-major
    gemm_bt<0, 1><<<dim3(256, 4), 256, 0, stream>>>(featsb, Wtp, bias512, thetaphi,
                                                    MM, 512, 1024);
    // H^T = Wgcn^T @ feats^T : [1024][32768] bf16 row-major (coalesced stores)
    gemm_bt<0, 1><<<dim3(8, 256), 256, 0, stream>>>(Wgt, featsb, nullptr, HtT,
                                                    1024, MM, 1024);
    // relation graph + out = relu(P @ H)
    fused_softmax_out<<<BB, 256, 0, stream>>>(thetaphi, boxes, HtT, out + RG_OFF, out);
}

// Round 4
// 436.171 us; speedup vs baseline: 1.1523x; 1.0863x over previous
//
#include <hip/hip_runtime.h>
#include <hip/hip_bf16.h>
#include <math.h>

// Shapes (fixed by the problem)
#define BB   512
#define NN   64
#define NFG  1024
#define NFR  256
#define MM   (BB * NN)          // 32768
#define RG_OFF 33554432L        // out elements before relation_graph

typedef __attribute__((ext_vector_type(8))) short bf16x8;   // 8 bf16 = 4 VGPRs (guide §3)
typedef __attribute__((ext_vector_type(4))) float f32x4;
typedef __attribute__((ext_vector_type(8))) unsigned short u16x8;

__device__ inline unsigned short f2bf(float f) {
    union { float f; unsigned u; } v; v.f = f;
    unsigned u = v.u;
    return (unsigned short)((u + 0x7FFFu + ((u >> 16) & 1u)) >> 16);  // RNE
}

__device__ inline void gld_lds16(const unsigned short* g, unsigned short* l) {
    // async global->LDS, 16B per lane; LDS dst is wave-uniform base + lane*16
    __builtin_amdgcn_global_load_lds((const __attribute__((address_space(1))) void*)g,
                                     (__attribute__((address_space(3))) void*)l, 16, 0, 0);
}

// ---------------- converts ----------------

__global__ __launch_bounds__(256) void cast_f32_bf16(const float* __restrict__ in,
                                                     unsigned short* __restrict__ out, long n) {
    long i = ((long)blockIdx.x * 256 + threadIdx.x) * 8;
    if (i + 8 <= n) {
        f32x4 a = *(const f32x4*)(in + i);
        f32x4 b = *(const f32x4*)(in + i + 4);
        u16x8 o;
#pragma unroll
        for (int c = 0; c < 4; ++c) { o[c] = f2bf(a[c]); o[4 + c] = f2bf(b[c]); }
        *(u16x8*)(out + i) = o;
    }
}

// in: [K][N] f32 row-major  ->  out: [N][K] bf16 row-major
__global__ void transpose_cast(const float* __restrict__ in, unsigned short* __restrict__ out,
                               int K, int N) {
    __shared__ float tile[32][33];
    int tx = threadIdx.x, ty = threadIdx.y;
    int k0 = blockIdx.y * 32, n0 = blockIdx.x * 32;
#pragma unroll
    for (int r = 0; r < 4; ++r)
        tile[ty + r * 8][tx] = in[(long)(k0 + ty + r * 8) * N + n0 + tx];
    __syncthreads();
#pragma unroll
    for (int r = 0; r < 4; ++r)
        out[(long)(n0 + ty + r * 8) * K + k0 + tx] = f2bf(tile[tx][ty + r * 8]);
}

__global__ void concat_bias(const float* __restrict__ bt, const float* __restrict__ bp,
                            float* __restrict__ out) {
    int i = threadIdx.x;
    out[i] = (i < 256) ? bt[i] : bp[i - 256];
}

// ---------------- gemm_bt: C[M][N] = act(A[M][K] @ Bt[N][K]^T + bias) ----------------
// 128x128 tile, 4 waves 2x2, each wave 64x64 (4x4 mfma 16x16x32 acc), BK=64.
// LDS rows are 128B (all 32 banks) -> XOR chunk swizzle keeps ds_read_b128 conflict-minimal.
// SWIZ: 0 none; 1 = B-operand reused (each XCD owns an ntile range, mtile fastest,
//       LOG_FAST=log2(gridDim.x)); 2 = A-operand reused (roles swapped,
//       LOG_FAST=log2(gridDim.y)). Keeps tile-sharing blocks on one XCD's L2.

template<int RELU, int STORE_BF16, int SWIZ, int LOG_FAST>
__global__ __launch_bounds__(256, 4)
void gemm_bt(const unsigned short* __restrict__ A, const unsigned short* __restrict__ Bt,
             const float* __restrict__ bias, void* __restrict__ Cout,
             int M, int N, int K) {
    __shared__ __align__(16) unsigned short As[128 * 64];   // 16 KB
    __shared__ __align__(16) unsigned short Bs[128 * 64];   // 16 KB
    const int t    = threadIdx.x;
    const int lane = t & 63;
    const int w    = t >> 6;
    const int l15  = lane & 15;
    const int q    = lane >> 4;

    long mtile, ntile;
    if (SWIZ == 1) {
        long linear = (long)blockIdx.y * gridDim.x + blockIdx.x;  // dispatch order, x fastest
        int  xcd  = (int)(linear & 7);
        long slot = linear >> 3;
        mtile = slot & ((1 << LOG_FAST) - 1);
        ntile = (long)xcd * (gridDim.y >> 3) + (slot >> LOG_FAST);
    } else if (SWIZ == 2) {
        long linear = (long)blockIdx.y * gridDim.x + blockIdx.x;
        int  xcd  = (int)(linear & 7);
        long slot = linear >> 3;
        ntile = slot & ((1 << LOG_FAST) - 1);
        mtile = (long)xcd * (gridDim.x >> 3) + (slot >> LOG_FAST);
    } else {
        mtile = blockIdx.x; ntile = blockIdx.y;
    }
    const long tileM = mtile * 128;
    const long tileN = ntile * 128;
    const int wm = (w & 1) * 64;
    const int wn = (w >> 1) * 64;

    f32x4 acc[4][4] = {};

    // staging: 4 issues per operand. issue i, thread t -> LDS chunkid = i*256+t
    //   -> LDS row = i*32 + (t>>3), LDS slot = t&7.
    // lane fetches GLOBAL chunk (t&7)^(row&7) so slot s of row r holds chunk s^(r&7).
    const int rS = t >> 3;                 // 0..31
    const int cS = (t & 7) ^ (rS & 7);     // swizzled global chunk
    const unsigned short* gA = A  + (tileM + rS) * (long)K + cS * 8;
    const unsigned short* gB = Bt + (tileN + rS) * (long)K + cS * 8;

    for (int kt = 0; kt < K; kt += 64) {
        __syncthreads();                 // protect LDS reuse
#pragma unroll
        for (int i = 0; i < 4; ++i) {
            gld_lds16(gA + (long)i * 32 * K + kt, As + (i * 256 + w * 64) * 8);
            gld_lds16(gB + (long)i * 32 * K + kt, Bs + (i * 256 + w * 64) * 8);
        }
        __syncthreads();                 // drain staging (compiler emits vmcnt(0))
#pragma unroll
        for (int ks = 0; ks < 2; ++ks) {
            const int slot = (ks * 4 + q) ^ (l15 & 7);   // row&7 == l15&7 (16|wm,mi*16)
            bf16x8 af[4], bf[4];
#pragma unroll
            for (int mi = 0; mi < 4; ++mi)
                af[mi] = *(const bf16x8*)(As + (wm + mi * 16 + l15) * 64 + slot * 8);
#pragma unroll
            for (int ni = 0; ni < 4; ++ni)
                bf[ni] = *(const bf16x8*)(Bs + (wn + ni * 16 + l15) * 64 + slot * 8);
#pragma unroll
            for (int mi = 0; mi < 4; ++mi)
#pragma unroll
                for (int ni = 0; ni < 4; ++ni)
                    acc[mi][ni] = __builtin_amdgcn_mfma_f32_16x16x32_bf16(af[mi], bf[ni],
                                                                          acc[mi][ni], 0, 0, 0);
        }
    }

    // epilogue: C/D layout col=lane&15, row=(lane>>4)*4+reg (verified m89/m91)
#pragma unroll
    for (int mi = 0; mi < 4; ++mi) {
#pragma unroll
        for (int ni = 0; ni < 4; ++ni) {
            long row0 = tileM + wm + mi * 16 + q * 4;
            long col  = tileN + wn + ni * 16 + l15;
            float bv = bias ? bias[col] : 0.f;
#pragma unroll
            for (int r = 0; r < 4; ++r) {
                float v = acc[mi][ni][r] + bv;
                if (RELU) v = fmaxf(v, 0.f);
                long idx = (row0 + r) * N + col;
                if (STORE_BF16) ((unsigned short*)Cout)[idx] = f2bf(v);
                else            ((float*)Cout)[idx] = v;
            }
        }
    }
}

// ---------------- fused: sim -> mask -> softmax -> rg + out = relu(P @ H) ----------------
// one block (256 thr, 4 waves) per batch element; H stored transposed: HtT[g][i], i=b*64+j

__global__ __launch_bounds__(256)
void fused_softmax_out(const unsigned short* __restrict__ thetaphi,  // [32768][512] bf16
                       const float* __restrict__ boxes,              // [512][64][4]
                       const unsigned short* __restrict__ HtT,       // [1024][32768] bf16
                       float* __restrict__ rg_out,                   // relation_graph f32
                       float* __restrict__ out) {                    // [512][64][1024] f32
    __shared__ __align__(16) float sim_s[64][68];
    __shared__ __align__(16) unsigned short Pb[64][72];   // 144B row stride: 16B-aligned
    __shared__ float cxs[64], cys[64];
    const int t    = threadIdx.x;
    const int b    = blockIdx.x;
    const int lane = t & 63;
    const int w    = t >> 6;
    const int l15  = lane & 15;
    const int q    = lane >> 4;

    if (t < 64) {
        float4 bx = *(const float4*)(boxes + ((long)b * 64 + t) * 4);
        cxs[t] = (bx.x + bx.z) * 0.5f;
        cys[t] = (bx.y + bx.w) * 0.5f;
    }

    // sim[i][j] = theta_i . phi_j / 16 ; wave w does rows w*16..w*16+15
    {
        f32x4 acc[4] = {};
        const unsigned short* thA = thetaphi + ((long)b * 64 + w * 16 + l15) * 512 + q * 8;
        const unsigned short* thB = thetaphi + ((long)b * 64 + l15) * 512 + 256 + q * 8;
#pragma unroll
        for (int kt = 0; kt < 256; kt += 32) {
            bf16x8 a = *(const bf16x8*)(thA + kt);
#pragma unroll
            for (int ni = 0; ni < 4; ++ni) {
                bf16x8 bb = *(const bf16x8*)(thB + (long)ni * 16 * 512 + kt);
                acc[ni] = __builtin_amdgcn_mfma_f32_16x16x32_bf16(a, bb, acc[ni], 0, 0, 0);
            }
        }
#pragma unroll
        for (int ni = 0; ni < 4; ++ni)
#pragma unroll
            for (int r = 0; r < 4; ++r)
                sim_s[w * 16 + q * 4 + r][ni * 16 + l15] = acc[ni][r] * 0.0625f;
    }
    __syncthreads();

    // softmax row i, 4 lanes per row each owning 16 cols; emit rg (f32) and P (bf16, A-layout)
    {
        const int i  = t >> 2;
        const int j0 = (t & 3) * 16;
        const float cxi = cxs[i], cyi = cys[i];
        const float thr = (float)(0.2 * 157.0);
        float vals[16];
        float mx = -__builtin_inff();
#pragma unroll
        for (int jj = 0; jj < 16; ++jj) {
            int j = j0 + jj;
            float dx = cxi - cxs[j];
            float dy = cyi - cys[j];
            bool msk = sqrtf(dx * dx + dy * dy) > thr;
            float s = msk ? -__builtin_inff() : sim_s[i][j];
            vals[jj] = s;
            mx = fmaxf(mx, s);
        }
        mx = fmaxf(mx, __shfl_xor(mx, 1, 64));
        mx = fmaxf(mx, __shfl_xor(mx, 2, 64));
        float sum = 0.f;
#pragma unroll
        for (int jj = 0; jj < 16; ++jj) {
            float e = (vals[jj] == -__builtin_inff()) ? 0.f : __expf(vals[jj] - mx);
            vals[jj] = e;
            sum += e;
        }
        sum += __shfl_xor(sum, 1, 64);
        sum += __shfl_xor(sum, 2, 64);
        float inv = 1.f / sum;   // self always unmasked -> sum > 0
#pragma unroll
        for (int jj = 0; jj < 16; ++jj) {
            int j = j0 + jj;
            float p = vals[jj] * inv;
            rg_out[((long)b * 64 + i) * 64 + j] = p;
            Pb[i][j] = f2bf(p);
        }
    }
    __syncthreads();

    // out[i][g] = relu( sum_j P[i][j] * H[j][g] ), K=64; B-frags from HtT[g][b*64+j]
    {
        const unsigned short* HtB = HtT + (long)b * 64;     // column offset
        float* outB = out + (long)b * 65536;                // [64][1024]
        bf16x8 af[4][2];
#pragma unroll
        for (int mi = 0; mi < 4; ++mi)
#pragma unroll
            for (int kk = 0; kk < 2; ++kk)
                af[mi][kk] = *(const bf16x8*)(&Pb[mi * 16 + l15][kk * 32 + q * 8]);
#pragma unroll 2
        for (int nt = 0; nt < 16; ++nt) {
            const int g0 = w * 256 + nt * 16;
            const unsigned short* hp = HtB + (long)(g0 + l15) * 32768 + q * 8;
            bf16x8 b0 = *(const bf16x8*)(hp);        // j = q*8..q*8+7
            bf16x8 b1 = *(const bf16x8*)(hp + 32);   // j = 32+q*8..
#pragma unroll
            for (int mi = 0; mi < 4; ++mi) {
                f32x4 acc = {};
                acc = __builtin_amdgcn_mfma_f32_16x16x32_bf16(af[mi][0], b0, acc, 0, 0, 0);
                acc = __builtin_amdgcn_mfma_f32_16x16x32_bf16(af[mi][1], b1, acc, 0, 0, 0);
#pragma unroll
                for (int r = 0; r < 4; ++r)
                    outB[(long)(mi * 16 + q * 4 + r) * 1024 + g0 + l15] = fmaxf(acc[r], 0.f);
            }
        }
    }
}

// ---------------- launch ----------------

extern "C" void kernel_launch(void* const* d_in, const int* in_sizes, int n_in,
                              void* d_out, int out_size, void* d_ws, size_t ws_size,
                              hipStream_t stream) {
    const float* feats   = (const float*)d_in[0];
    const float* boxes   = (const float*)d_in[1];
    const float* W_theta = (const float*)d_in[2];
    const float* b_theta = (const float*)d_in[3];
    const float* W_phi   = (const float*)d_in[4];
    const float* b_phi   = (const float*)d_in[5];
    const float* W_gcn   = (const float*)d_in[6];
    float* out = (float*)d_out;

    // workspace layout (~171 MB)
    char* ws = (char*)d_ws;
    unsigned short* featsb   = (unsigned short*)(ws);                // 67108864 B
    unsigned short* thetaphi = (unsigned short*)(ws + 67108864);     // 33554432 B
    unsigned short* HtT      = (unsigned short*)(ws + 100663296);    // 67108864 B
    unsigned short* Wtp      = (unsigned short*)(ws + 167772160);    //  1048576 B
    unsigned short* Wgt      = (unsigned short*)(ws + 168820736);    //  2097152 B
    float*          bias512  = (float*)(ws + 170917888);             //     2048 B

    cast_f32_bf16<<<16384, 256, 0, stream>>>(feats, featsb, 33554432L);
    transpose_cast<<<dim3(8, 32),  dim3(32, 8), 0, stream>>>(W_theta, Wtp,              1024, 256);
    transpose_cast<<<dim3(8, 32),  dim3(32, 8), 0, stream>>>(W_phi,   Wtp + 256 * 1024, 1024, 256);
    transpose_cast<<<dim3(32, 32), dim3(32, 8), 0, stream>>>(W_gcn,   Wgt,              1024, 1024);
    concat_bias<<<1, 512, 0, stream>>>(b_theta, b_phi, bias512);

    // theta|phi: [32768][512] bf16 row-major. A=featsb reused by 4 ntiles -> SWIZ=2
    gemm_bt<0, 1, 2, 2><<<dim3(256, 4), 256, 0, stream>>>(featsb, Wtp, bias512, thetaphi,
                                                          MM, 512, 1024);
    // H^T = Wgcn^T @ feats^T : [1024][32768] bf16. B=featsb reused by 8 mtiles -> SWIZ=1
    gemm_bt<0, 1, 1, 3><<<dim3(8, 256), 256, 0, stream>>>(Wgt, featsb, nullptr, HtT,
                                                          1024, MM, 1024);
    // relation graph + out = relu(P @ H)
    fused_softmax_out<<<BB, 256, 0, stream>>>(thetaphi, boxes, HtT, out + RG_OFF, out);
}